// Round 6
// baseline (275.234 us; speedup 1.0000x reference)
//
#include <hip/hip_runtime.h>
#include <math.h>

#define NNODES 50000
#define NEDGES 800000
#define COUT 64
#define TILE_E 64
#define NTILES (NEDGES / TILE_E)   // 12500, exact
#define GRID 1024                  // 256 CU x 4 blocks
#define KEY_NEG_INF 0x007FFFFFu    // fkey(-inf)
#define NKEYS (2 * NNODES)         // sort key = t*NNODES + dst
#define NPB 391                    // ceil(NKEYS/256)

typedef short bf16x8 __attribute__((ext_vector_type(8)));
typedef float f32x4 __attribute__((ext_vector_type(4)));
#define MFMA16 __builtin_amdgcn_mfma_f32_16x16x32_bf16

// fp32 -> bf16 RTNE
__device__ __forceinline__ unsigned short f2bf(float x) {
    union { float f; unsigned u; } v; v.f = x;
    unsigned r = v.u + 0x7fffu + ((v.u >> 16) & 1u);
    return (unsigned short)(r >> 16);
}

// order-preserving float -> uint key
__device__ __forceinline__ unsigned fkey(float v) {
    unsigned u = __float_as_uint(v);
    return u ^ ((unsigned)((int)u >> 31) | 0x80000000u);
}

// ---------------------------------------------------------------------------
// prep: feat f32 -> bf16 table; out <- key(-inf); cnt <- 0
// ---------------------------------------------------------------------------
__global__ void prep_kernel(const float* __restrict__ feat, unsigned short* __restrict__ featbf,
                            unsigned* __restrict__ out, unsigned* __restrict__ cnt) {
    int i = blockIdx.x * blockDim.x + threadIdx.x;
    int st = gridDim.x * blockDim.x;
    for (int j = i; j < (NNODES * COUT) / 8; j += st) {
        const float4* pp = (const float4*)(feat + (size_t)j * 8);
        float4 x = pp[0], y = pp[1];
        union { unsigned short u[8]; uint4 v; } r;
        r.u[0] = f2bf(x.x); r.u[1] = f2bf(x.y); r.u[2] = f2bf(x.z); r.u[3] = f2bf(x.w);
        r.u[4] = f2bf(y.x); r.u[5] = f2bf(y.y); r.u[6] = f2bf(y.z); r.u[7] = f2bf(y.w);
        ((uint4*)featbf)[j] = r.v;
    }
    for (int j = i; j < NNODES * COUT; j += st) out[j] = KEY_NEG_INF;
    for (int j = i; j < NKEYS; j += st) cnt[j] = 0u;
}

__global__ void hist_kernel(const int* __restrict__ ei, const int* __restrict__ ea,
                            unsigned* __restrict__ cnt) {
    int i = blockIdx.x * blockDim.x + threadIdx.x;
    int st = gridDim.x * blockDim.x;
    for (int e = i; e < NEDGES; e += st)
        atomicAdd(&cnt[ea[e] * NNODES + ei[NEDGES + e]], 1u);
}

__global__ __launch_bounds__(256) void partial_kernel(const unsigned* __restrict__ cnt,
                                                      unsigned* __restrict__ part) {
    __shared__ unsigned ws[4];
    const int t = threadIdx.x;
    const int i = blockIdx.x * 256 + t;
    unsigned v = (i < NKEYS) ? cnt[i] : 0u;
    #pragma unroll
    for (int off = 32; off; off >>= 1) v += __shfl_down(v, off, 64);
    if ((t & 63) == 0) ws[t >> 6] = v;
    __syncthreads();
    if (t == 0) part[blockIdx.x] = ws[0] + ws[1] + ws[2] + ws[3];
}

// exclusive scan of part[NPB] (one 512-thread block)
__global__ __launch_bounds__(512) void scanpart_kernel(const unsigned* __restrict__ part,
                                                       unsigned* __restrict__ partx) {
    __shared__ unsigned wsum[8];
    const int t = threadIdx.x, lane = t & 63, wv = t >> 6;
    unsigned orig = (t < NPB) ? part[t] : 0u;
    unsigned v = orig;
    #pragma unroll
    for (int off = 1; off < 64; off <<= 1) {
        unsigned n = __shfl_up(v, off, 64);
        if (lane >= off) v += n;
    }
    if (lane == 63) wsum[wv] = v;
    __syncthreads();
    unsigned wo = 0;
    #pragma unroll
    for (int k = 0; k < 8; ++k) if (k < wv) wo += wsum[k];
    if (t < NPB) partx[t] = wo + v - orig;
}

__global__ __launch_bounds__(256) void cursor_kernel(const unsigned* __restrict__ cnt,
                                                     const unsigned* __restrict__ partx,
                                                     unsigned* __restrict__ cursor) {
    __shared__ unsigned sh[256];
    const int t = threadIdx.x;
    const int i = blockIdx.x * 256 + t;
    unsigned v = (i < NKEYS) ? cnt[i] : 0u;
    sh[t] = v;
    __syncthreads();
    for (int off = 1; off < 256; off <<= 1) {
        unsigned add = (t >= off) ? sh[t - off] : 0u;
        __syncthreads();
        sh[t] += add;
        __syncthreads();
    }
    if (i < NKEYS) cursor[i] = partx[blockIdx.x] + sh[t] - v;
}

// scatter packed records into (t,dst)-sorted order: {src|t<<20, dst|t<<20}
__global__ void scatter_kernel(const int* __restrict__ ei, const int* __restrict__ ea,
                               unsigned* __restrict__ cursor, int2* __restrict__ rec) {
    int i = blockIdx.x * blockDim.x + threadIdx.x;
    int st = gridDim.x * blockDim.x;
    for (int e = i; e < NEDGES; e += st) {
        int d = ei[NEDGES + e];
        int t = ea[e];
        unsigned p = atomicAdd(&cursor[t * NNODES + d], 1u);
        rec[p] = make_int2(ei[e] | (t << 20), d | (t << 20));
    }
}

__global__ void finalize_kernel(float* __restrict__ out, int n) {
    int i = blockIdx.x * blockDim.x + threadIdx.x;
    int stride = gridDim.x * blockDim.x;
    for (; i < n; i += stride) {
        unsigned k = ((unsigned*)out)[i];
        unsigned u = (k & 0x80000000u) ? (k ^ 0x80000000u) : ~k;
        out[i] = (u == 0xFF800000u) ? 0.0f : __uint_as_float(u);
    }
}

// ---------------------------------------------------------------------------
// MFMA edge kernel, (t,dst)-sorted tiles (type-uniform except <=1 tile).
//  K=96: k0..63 feat (pre-bf16 table), k64..71 tail [ps,diff,dist,1], k72..95
//  ZERO W rows (A side reads tail broadcast there -> finite x 0).
//  Afeat [row][chunk^(row&7)] stride 128B: staging writes + frag reads at
//  b128 floor. W frags in registers (2 types x 2 cols x 3 ks).
//  Kt swizzle er*64 + (col ^ ((er<<2)&31)): writes/reads 2-way (free).
// ---------------------------------------------------------------------------
__global__ __launch_bounds__(256, 4) void edge_mfma_kernel(
    const unsigned short* __restrict__ featbf, const float* __restrict__ pos,
    const float* __restrict__ W, const float* __restrict__ b,
    const int2* __restrict__ rec, unsigned* __restrict__ out)
{
    __shared__ char SMEM[26112];
    bf16x8*   Afeat = (bf16x8*)SMEM;              // [64][8] 16B units, 8192 B
    bf16x8*   Atail = (bf16x8*)(SMEM + 8192);     // [64], 1024 B
    unsigned* Kt    = (unsigned*)(SMEM + 9216);   // [4096], 16384 B
    int*      dstv  = (int*)(SMEM + 25600);       // [2][64]

    const int tid = threadIdx.x;
    const int lane = tid & 63, w = tid >> 6;
    const int rg = w >> 1, cg = w & 1;
    const int la = lane & 15, lh = lane >> 4;

    // ---- stage W_aug [t][col][k0..95] bf16 into SMEM (one-time) ----
    {
        unsigned short* Ws = (unsigned short*)SMEM;   // 24576 B
        for (int idx = tid; idx < 2 * 96 * 64; idx += 256) {
            int k = idx >> 6, j = idx & 63;           // k 0..191, coalesced over j
            int t = (k >= 96);
            int kk = k - t * 96;
            float v = 0.0f;
            if (kk < 71)       v = W[(t * 71 + kk) * 64 + j];
            else if (kk == 71) v = b[t * 64 + j];
            Ws[(t * 64 + j) * 96 + kk] = f2bf(v);
        }
    }
    __syncthreads();
    bf16x8 wt0c0k0, wt0c0k1, wt0c0k2, wt0c1k0, wt0c1k1, wt0c1k2;
    bf16x8 wt1c0k0, wt1c0k1, wt1c0k2, wt1c1k0, wt1c1k1, wt1c1k2;
    {
        const bf16x8* Wv = (const bf16x8*)SMEM;       // idx = (t*64+col)*12 + ks*4+lh
        const int c0 = cg * 32 + la, c1 = c0 + 16;
        wt0c0k0 = Wv[(c0)*12 + 0 + lh];  wt0c0k1 = Wv[(c0)*12 + 4 + lh];  wt0c0k2 = Wv[(c0)*12 + 8 + lh];
        wt0c1k0 = Wv[(c1)*12 + 0 + lh];  wt0c1k1 = Wv[(c1)*12 + 4 + lh];  wt0c1k2 = Wv[(c1)*12 + 8 + lh];
        wt1c0k0 = Wv[(64+c0)*12 + 0 + lh]; wt1c0k1 = Wv[(64+c0)*12 + 4 + lh]; wt1c0k2 = Wv[(64+c0)*12 + 8 + lh];
        wt1c1k0 = Wv[(64+c1)*12 + 0 + lh]; wt1c1k1 = Wv[(64+c1)*12 + 4 + lh]; wt1c1k2 = Wv[(64+c1)*12 + 8 + lh];
    }
    __syncthreads();    // frags held; SMEM now reusable for tiles

    const int row = tid >> 2, c = tid & 3;

    int it = 0;
    for (int tile = blockIdx.x; tile < NTILES; tile += GRID, ++it) {
        const int p = it & 1;
        // ---------------- stage 64 edges ----------------
        const int2 r2 = rec[tile * TILE_E + row];
        const int src = r2.x & 0xFFFFF;
        const int rx = row & 7;

        const uint4* g = (const uint4*)(featbf + (size_t)src * 64);   // 8x16B chunks
        uint4 q0 = g[2 * c], q1 = g[2 * c + 1];
        *(uint4*)&Afeat[row * 8 + ((2 * c) ^ rx)]     = q0;
        *(uint4*)&Afeat[row * 8 + ((2 * c + 1) ^ rx)] = q1;

        if (c == 3) {
            int dst = r2.y & 0xFFFFF;
            float ps0 = pos[src * 3], ps1 = pos[src * 3 + 1], ps2 = pos[src * 3 + 2];
            float d0 = pos[dst * 3] - ps0, d1 = pos[dst * 3 + 1] - ps1, d2 = pos[dst * 3 + 2] - ps2;
            float dist = sqrtf(d0 * d0 + d1 * d1 + d2 * d2);
            union { bf16x8 v; unsigned short u[8]; } pt;
            pt.u[0] = f2bf(ps0); pt.u[1] = f2bf(ps1); pt.u[2] = f2bf(ps2);
            pt.u[3] = f2bf(d0);  pt.u[4] = f2bf(d1);  pt.u[5] = f2bf(d2);
            pt.u[6] = f2bf(dist); pt.u[7] = f2bf(1.0f);
            Atail[row] = pt.v;
            dstv[p * 64 + row] = r2.y;   // dst | t<<20
        }
        __syncthreads();                                   // B1: tile staged

        // ---------------- fragment loads ----------------
        const int row0 = rg * 32 + la, row1 = row0 + 16;
        const int frx = la & 7;                            // row0&7 == row1&7
        bf16x8 a00 = Afeat[row0 * 8 + (lh ^ frx)];
        bf16x8 a01 = Afeat[row0 * 8 + ((4 + lh) ^ frx)];
        bf16x8 a0t = Atail[row0];
        bf16x8 a10 = Afeat[row1 * 8 + (lh ^ frx)];
        bf16x8 a11 = Afeat[row1 * 8 + ((4 + lh) ^ frx)];
        bf16x8 a1t = Atail[row1];

        const int tt0 = (dstv[p * 64 + 0] >> 20) & 1;
        const int tt63 = (dstv[p * 64 + 63] >> 20) & 1;
        const int col0 = cg * 32 + la, col1 = col0 + 16;

#define DO12(P00,P01,P10,P11,T) \
        P00 = MFMA16(a00, wt##T##c0k0, P00,0,0,0); P00 = MFMA16(a01, wt##T##c0k1, P00,0,0,0); P00 = MFMA16(a0t, wt##T##c0k2, P00,0,0,0); \
        P01 = MFMA16(a00, wt##T##c1k0, P01,0,0,0); P01 = MFMA16(a01, wt##T##c1k1, P01,0,0,0); P01 = MFMA16(a0t, wt##T##c1k2, P01,0,0,0); \
        P10 = MFMA16(a10, wt##T##c0k0, P10,0,0,0); P10 = MFMA16(a11, wt##T##c0k1, P10,0,0,0); P10 = MFMA16(a1t, wt##T##c0k2, P10,0,0,0); \
        P11 = MFMA16(a10, wt##T##c1k0, P11,0,0,0); P11 = MFMA16(a11, wt##T##c1k1, P11,0,0,0); P11 = MFMA16(a1t, wt##T##c1k2, P11,0,0,0);

        if (tt0 == tt63) {
            f32x4 acc00 = {0,0,0,0}, acc01 = {0,0,0,0}, acc10 = {0,0,0,0}, acc11 = {0,0,0,0};
            if (tt0 == 0) { DO12(acc00, acc01, acc10, acc11, 0) }
            else          { DO12(acc00, acc01, acc10, acc11, 1) }
            #pragma unroll
            for (int i = 0; i < 4; ++i) {
                int e0 = rg * 32 + lh * 4 + i, e1 = e0 + 16;
                Kt[e0 * 64 + (col0 ^ ((e0 << 2) & 31))] = fkey(acc00[i]);
                Kt[e0 * 64 + (col1 ^ ((e0 << 2) & 31))] = fkey(acc01[i]);
                Kt[e1 * 64 + (col0 ^ ((e1 << 2) & 31))] = fkey(acc10[i]);
                Kt[e1 * 64 + (col1 ^ ((e1 << 2) & 31))] = fkey(acc11[i]);
            }
        } else {
            // mixed-type tile (<=1 of 12500): compute both, select per row
            f32x4 pA00 = {0,0,0,0}, pA01 = {0,0,0,0}, pA10 = {0,0,0,0}, pA11 = {0,0,0,0};
            f32x4 pB00 = {0,0,0,0}, pB01 = {0,0,0,0}, pB10 = {0,0,0,0}, pB11 = {0,0,0,0};
            DO12(pA00, pA01, pA10, pA11, 0)
            DO12(pB00, pB01, pB10, pB11, 1)
            #pragma unroll
            for (int i = 0; i < 4; ++i) {
                int e0 = rg * 32 + lh * 4 + i, e1 = e0 + 16;
                int s0 = (dstv[p * 64 + e0] >> 20) & 1;
                int s1 = (dstv[p * 64 + e1] >> 20) & 1;
                Kt[e0 * 64 + (col0 ^ ((e0 << 2) & 31))] = fkey(s0 ? pB00[i] : pA00[i]);
                Kt[e0 * 64 + (col1 ^ ((e0 << 2) & 31))] = fkey(s0 ? pB01[i] : pA01[i]);
                Kt[e1 * 64 + (col0 ^ ((e1 << 2) & 31))] = fkey(s1 ? pB10[i] : pA10[i]);
                Kt[e1 * 64 + (col1 ^ ((e1 << 2) & 31))] = fkey(s1 ? pB11[i] : pA11[i]);
            }
        }
#undef DO12
        __syncthreads();                                   // B2: keys visible

        // ---- segmented max: thread (col, 16-row quarter), sorted keys ----
        {
            const int colr = tid & 63;
            const int rbeg = (tid >> 6) * 16;
            unsigned cur = Kt[rbeg * 64 + (colr ^ ((rbeg << 2) & 31))];
            int curd = dstv[p * 64 + rbeg];
            #pragma unroll
            for (int r = rbeg + 1; r < rbeg + 16; ++r) {
                unsigned k = Kt[r * 64 + (colr ^ ((r << 2) & 31))];
                int d = dstv[p * 64 + r];
                if (d != curd) {
                    atomicMax(out + (size_t)(curd & 0xFFFFF) * COUT + colr, cur);
                    curd = d; cur = k;
                } else {
                    cur = (k > cur) ? k : cur;
                }
            }
            atomicMax(out + (size_t)(curd & 0xFFFFF) * COUT + colr, cur);
        }
        // next staging: Afeat/Atail reads all pre-B2; dstv double-buffered;
        // Kt(n+1) writes gated by B1(n+1).
    }
}

extern "C" void kernel_launch(void* const* d_in, const int* in_sizes, int n_in,
                              void* d_out, int out_size, void* d_ws, size_t ws_size,
                              hipStream_t stream) {
    const float* feat = (const float*)d_in[0];
    const float* pos  = (const float*)d_in[1];
    const float* W    = (const float*)d_in[2];
    const float* b    = (const float*)d_in[3];
    const int*   ei   = (const int*)d_in[4];
    const int*   ea   = (const int*)d_in[5];
    unsigned* out = (unsigned*)d_out;

    // ws: featbf 6.4MB | rec 6.4MB | cnt 400KB | cursor 400KB | part | partx
    unsigned short* featbf = (unsigned short*)d_ws;
    int2*     rec    = (int2*)((char*)d_ws + (size_t)NNODES * COUT * 2);
    unsigned* cnt    = (unsigned*)(rec + NEDGES);
    unsigned* cursor = cnt + NKEYS;
    unsigned* part   = cursor + NKEYS;
    unsigned* partx  = part + NPB;

    prep_kernel<<<2048, 256, 0, stream>>>(feat, featbf, out, cnt);
    hist_kernel<<<2048, 256, 0, stream>>>(ei, ea, cnt);
    partial_kernel<<<NPB, 256, 0, stream>>>(cnt, part);
    scanpart_kernel<<<1, 512, 0, stream>>>(part, partx);
    cursor_kernel<<<NPB, 256, 0, stream>>>(cnt, partx, cursor);
    scatter_kernel<<<2048, 256, 0, stream>>>(ei, ea, cursor, rec);
    edge_mfma_kernel<<<GRID, 256, 0, stream>>>(featbf, pos, W, b, rec, out);
    finalize_kernel<<<2048, 256, 0, stream>>>((float*)out, NNODES * COUT);
}

// Round 7
// 241.072 us; speedup vs baseline: 1.1417x; 1.1417x over previous
//
#include <hip/hip_runtime.h>
#include <math.h>

#define NNODES 50000
#define NEDGES 800000
#define COUT 64
#define TILE_E 64
#define NTILES (NEDGES / TILE_E)   // 12500, exact
#define GRID 1024                  // 256 CU x 4 blocks
#define KEY_NEG_INF 0x007FFFFFu    // fkey(-inf)
#define NPB 196                    // ceil(NNODES/256) scan blocks

typedef short bf16x8 __attribute__((ext_vector_type(8)));
typedef float f32x4 __attribute__((ext_vector_type(4)));
#define MFMA16 __builtin_amdgcn_mfma_f32_16x16x32_bf16

// fp32 -> bf16 RTNE
__device__ __forceinline__ unsigned short f2bf(float x) {
    union { float f; unsigned u; } v; v.f = x;
    unsigned r = v.u + 0x7fffu + ((v.u >> 16) & 1u);
    return (unsigned short)(r >> 16);
}

// order-preserving float -> uint key
__device__ __forceinline__ unsigned fkey(float v) {
    unsigned u = __float_as_uint(v);
    return u ^ ((unsigned)((int)u >> 31) | 0x80000000u);
}

// ---------------------------------------------------------------------------
// prep: feat f32 -> bf16 table; out <- key(-inf); cnt <- 0
// ---------------------------------------------------------------------------
__global__ void prep_kernel(const float* __restrict__ feat, unsigned short* __restrict__ featbf,
                            unsigned* __restrict__ out, unsigned* __restrict__ cnt) {
    int i = blockIdx.x * blockDim.x + threadIdx.x;
    int st = gridDim.x * blockDim.x;
    for (int j = i; j < (NNODES * COUT) / 8; j += st) {
        const float4* pp = (const float4*)(feat + (size_t)j * 8);
        float4 x = pp[0], y = pp[1];
        union { unsigned short u[8]; uint4 v; } r;
        r.u[0] = f2bf(x.x); r.u[1] = f2bf(x.y); r.u[2] = f2bf(x.z); r.u[3] = f2bf(x.w);
        r.u[4] = f2bf(y.x); r.u[5] = f2bf(y.y); r.u[6] = f2bf(y.z); r.u[7] = f2bf(y.w);
        ((uint4*)featbf)[j] = r.v;
    }
    for (int j = i; j < NNODES * COUT; j += st) out[j] = KEY_NEG_INF;
    for (int j = i; j < NNODES; j += st) cnt[j] = 0u;
}

__global__ void hist_kernel(const int* __restrict__ ei, unsigned* __restrict__ cnt) {
    int i = blockIdx.x * blockDim.x + threadIdx.x;
    int st = gridDim.x * blockDim.x;
    for (int e = i; e < NEDGES; e += st) atomicAdd(&cnt[ei[NEDGES + e]], 1u);
}

__global__ __launch_bounds__(256) void partial_kernel(const unsigned* __restrict__ cnt,
                                                      unsigned* __restrict__ part) {
    __shared__ unsigned ws[4];
    const int t = threadIdx.x;
    const int i = blockIdx.x * 256 + t;
    unsigned v = (i < NNODES) ? cnt[i] : 0u;
    #pragma unroll
    for (int off = 32; off; off >>= 1) v += __shfl_down(v, off, 64);
    if ((t & 63) == 0) ws[t >> 6] = v;
    __syncthreads();
    if (t == 0) part[blockIdx.x] = ws[0] + ws[1] + ws[2] + ws[3];
}

// exclusive scan of part[196] (single small block)
__global__ __launch_bounds__(256) void scanpart_kernel(const unsigned* __restrict__ part,
                                                       unsigned* __restrict__ partx) {
    __shared__ unsigned wsum[4];
    const int t = threadIdx.x, lane = t & 63, wv = t >> 6;
    unsigned orig = (t < NPB) ? part[t] : 0u;
    unsigned v = orig;
    #pragma unroll
    for (int off = 1; off < 64; off <<= 1) {
        unsigned n = __shfl_up(v, off, 64);
        if (lane >= off) v += n;
    }
    if (lane == 63) wsum[wv] = v;
    __syncthreads();
    unsigned wo = 0;
    #pragma unroll
    for (int k = 0; k < 4; ++k) if (k < wv) wo += wsum[k];
    if (t < NPB) partx[t] = wo + v - orig;
}

__global__ __launch_bounds__(256) void cursor_kernel(const unsigned* __restrict__ cnt,
                                                     const unsigned* __restrict__ partx,
                                                     unsigned* __restrict__ cursor) {
    __shared__ unsigned sh[256];
    const int t = threadIdx.x;
    const int i = blockIdx.x * 256 + t;
    unsigned v = (i < NNODES) ? cnt[i] : 0u;
    sh[t] = v;
    __syncthreads();
    for (int off = 1; off < 256; off <<= 1) {
        unsigned add = (t >= off) ? sh[t - off] : 0u;
        __syncthreads();
        sh[t] += add;
        __syncthreads();
    }
    if (i < NNODES) cursor[i] = partx[blockIdx.x] + sh[t] - v;
}

// scatter packed records into dst-sorted order: {src | t<<20, dst}
__global__ void scatter_kernel(const int* __restrict__ ei, const int* __restrict__ ea,
                               unsigned* __restrict__ cursor, int2* __restrict__ rec) {
    int i = blockIdx.x * blockDim.x + threadIdx.x;
    int st = gridDim.x * blockDim.x;
    for (int e = i; e < NEDGES; e += st) {
        int d = ei[NEDGES + e];
        unsigned p = atomicAdd(&cursor[d], 1u);
        rec[p] = make_int2(ei[e] | (ea[e] << 20), d);
    }
}

__global__ void finalize_kernel(float* __restrict__ out, int n) {
    int i = blockIdx.x * blockDim.x + threadIdx.x;
    int stride = gridDim.x * blockDim.x;
    for (; i < n; i += stride) {
        unsigned k = ((unsigned*)out)[i];
        unsigned u = (k & 0x80000000u) ? (k ^ 0x80000000u) : ~k;
        out[i] = (u == 0xFF800000u) ? 0.0f : __uint_as_float(u);
    }
}

// ---------------------------------------------------------------------------
// MFMA edge kernel over dst-sorted records (round-5 structure + featbf + fixed
// Kt swizzle). K=160 augmented: type block t holds slots [10t..10t+9]:
//   slots 0-7 feat (from bf16 table), slot 8 tail [ps,diff,dist,1], slot 9
//   garbage (W rows 72..79 are zero); mirror type block slots 0-8 zeroed,
//   slot 9+19 zeroed ONCE (initial LDS could be NaN).
// A layout [slot][row] (20x64x16B = 20480B). W frags in 10 regs/wave.
// Kt [64][64] u32, swizzle er*64 + (col ^ ((er<<2)&31)): 2-way = free.
// 2 barriers/tile; dstv double-buffered; segscan flushes 1 atomic/run.
// ---------------------------------------------------------------------------
__global__ __launch_bounds__(256, 4) void edge_mfma_kernel(
    const unsigned short* __restrict__ featbf, const float* __restrict__ pos,
    const float* __restrict__ W, const float* __restrict__ b,
    const int2* __restrict__ rec, unsigned* __restrict__ out)
{
    __shared__ char SMEM[37376];
    bf16x8*   Amsg = (bf16x8*)SMEM;               // [20][64] 16B units, 20480 B
    unsigned* Kt   = (unsigned*)(SMEM + 20480);   // [4096], 16384 B
    int*      dstv = (int*)(SMEM + 36864);        // [2][64]

    const int tid = threadIdx.x;
    const int lane = tid & 63, w = tid >> 6;
    const int rg = w >> 1, cg = w & 1;
    const int la = lane & 15, lh = lane >> 4;
    const bf16x8 zero8 = {0, 0, 0, 0, 0, 0, 0, 0};

    // ---- stage W_aug [col j][k 0..159] bf16 into SMEM (one-time) ----
    {
        unsigned short* Ws = (unsigned short*)SMEM;   // 64*160*2 = 20480 B
        for (int idx = tid; idx < 160 * 64; idx += 256) {
            int k = idx >> 6, j = idx & 63;           // coalesced over j
            int t = (k >= 80);
            int kk = k - t * 80;
            float v = 0.0f;
            if (kk < 71)       v = W[(t * 71 + kk) * 64 + j];
            else if (kk == 71) v = b[t * 64 + j];
            Ws[j * 160 + k] = f2bf(v);
        }
    }
    __syncthreads();
    bf16x8 wb0[5], wb1[5];
    {
        const bf16x8* Wv = (const bf16x8*)SMEM;       // frag = Wv[col*20 + slot]
        const int c0 = cg * 32 + la, c1 = c0 + 16;
        #pragma unroll
        for (int ks = 0; ks < 5; ++ks) {
            wb0[ks] = Wv[c0 * 20 + ks * 4 + lh];
            wb1[ks] = Wv[c1 * 20 + ks * 4 + lh];
        }
    }
    __syncthreads();                                  // all frags held
    // one-time zero of slots 9 and 19 (never written in the loop)
    if (tid < 128) {
        Amsg[(9 + (tid >> 6) * 10) * 64 + (tid & 63)] = zero8;
    }
    __syncthreads();

    const int row = tid >> 2, c = tid & 3;

    int it = 0;
    for (int tile = blockIdx.x; tile < NTILES; tile += GRID, ++it) {
        const int p = it & 1;
        // ---------------- stage 64 sorted edges ----------------
        const int2 r2 = rec[tile * TILE_E + row];
        const int src = r2.x & 0xFFFFF;
        const int t = r2.x >> 20;
        const int ot = 1 - t;

        const uint4* g = (const uint4*)(featbf + (size_t)src * 64);   // 8x16B
        uint4 q0 = g[2 * c], q1 = g[2 * c + 1];
        *(uint4*)&Amsg[(t * 10 + 2 * c) * 64 + row]     = q0;
        *(uint4*)&Amsg[(t * 10 + 2 * c + 1) * 64 + row] = q1;
        Amsg[(ot * 10 + 2 * c) * 64 + row]     = zero8;
        Amsg[(ot * 10 + 2 * c + 1) * 64 + row] = zero8;

        if (c == 0) {
            int dst = r2.y;
            float ps0 = pos[src * 3], ps1 = pos[src * 3 + 1], ps2 = pos[src * 3 + 2];
            float d0 = pos[dst * 3] - ps0, d1 = pos[dst * 3 + 1] - ps1, d2 = pos[dst * 3 + 2] - ps2;
            float dist = sqrtf(d0 * d0 + d1 * d1 + d2 * d2);
            union { bf16x8 v; unsigned short u[8]; } pt;
            pt.u[0] = f2bf(ps0); pt.u[1] = f2bf(ps1); pt.u[2] = f2bf(ps2);
            pt.u[3] = f2bf(d0);  pt.u[4] = f2bf(d1);  pt.u[5] = f2bf(d2);
            pt.u[6] = f2bf(dist); pt.u[7] = f2bf(1.0f);
            Amsg[(t * 10 + 8) * 64 + row] = pt.v;
        } else if (c == 1) {
            Amsg[(ot * 10 + 8) * 64 + row] = zero8;
        } else if (c == 3) {
            dstv[p * 64 + row] = r2.y;
        }
        __syncthreads();                                   // B1: tile staged

        // ---------------- mfma: 32x32 tile per wave, W from regs ----------------
        f32x4 acc00 = {0,0,0,0}, acc01 = {0,0,0,0}, acc10 = {0,0,0,0}, acc11 = {0,0,0,0};
        const int r0 = rg * 32 + la, r1 = r0 + 16;
        #pragma unroll
        for (int ks = 0; ks < 5; ++ks) {
            bf16x8 a0 = Amsg[(ks * 4 + lh) * 64 + r0];
            bf16x8 a1 = Amsg[(ks * 4 + lh) * 64 + r1];
            acc00 = MFMA16(a0, wb0[ks], acc00, 0, 0, 0);
            acc01 = MFMA16(a0, wb1[ks], acc01, 0, 0, 0);
            acc10 = MFMA16(a1, wb0[ks], acc10, 0, 0, 0);
            acc11 = MFMA16(a1, wb1[ks], acc11, 0, 0, 0);
        }

        // ---------------- keys -> Kt (swizzled, 2-way free) ----------------
        const int col0 = cg * 32 + la, col1 = col0 + 16;
        #pragma unroll
        for (int i = 0; i < 4; ++i) {
            int e0 = rg * 32 + lh * 4 + i, e1 = e0 + 16;
            Kt[e0 * 64 + (col0 ^ ((e0 << 2) & 31))] = fkey(acc00[i]);
            Kt[e0 * 64 + (col1 ^ ((e0 << 2) & 31))] = fkey(acc01[i]);
            Kt[e1 * 64 + (col0 ^ ((e1 << 2) & 31))] = fkey(acc10[i]);
            Kt[e1 * 64 + (col1 ^ ((e1 << 2) & 31))] = fkey(acc11[i]);
        }
        __syncthreads();                                   // B2: keys visible

        // ---- segmented max: thread (col, 16-row quarter), sorted dsts ----
        {
            const int colr = tid & 63;
            const int rbeg = (tid >> 6) * 16;
            unsigned cur = Kt[rbeg * 64 + (colr ^ ((rbeg << 2) & 31))];
            int curd = dstv[p * 64 + rbeg];
            #pragma unroll
            for (int r = rbeg + 1; r < rbeg + 16; ++r) {
                unsigned k = Kt[r * 64 + (colr ^ ((r << 2) & 31))];
                int d = dstv[p * 64 + r];
                if (d != curd) {
                    atomicMax(out + (size_t)curd * COUT + colr, cur);
                    curd = d; cur = k;
                } else {
                    cur = (k > cur) ? k : cur;
                }
            }
            atomicMax(out + (size_t)curd * COUT + colr, cur);
        }
        // next staging: Amsg writes land in slots read before B2; dstv is
        // double-buffered; Kt(n+1) writes are gated by B1(n+1).
    }
}

extern "C" void kernel_launch(void* const* d_in, const int* in_sizes, int n_in,
                              void* d_out, int out_size, void* d_ws, size_t ws_size,
                              hipStream_t stream) {
    const float* feat = (const float*)d_in[0];
    const float* pos  = (const float*)d_in[1];
    const float* W    = (const float*)d_in[2];
    const float* b    = (const float*)d_in[3];
    const int*   ei   = (const int*)d_in[4];
    const int*   ea   = (const int*)d_in[5];
    unsigned* out = (unsigned*)d_out;

    // ws: featbf 6.4MB | rec 6.4MB | cnt 200KB | cursor 200KB | part | partx
    unsigned short* featbf = (unsigned short*)d_ws;
    int2*     rec    = (int2*)((char*)d_ws + (size_t)NNODES * COUT * 2);
    unsigned* cnt    = (unsigned*)(rec + NEDGES);
    unsigned* cursor = cnt + NNODES;
    unsigned* part   = cursor + NNODES;
    unsigned* partx  = part + NPB;

    prep_kernel<<<2048, 256, 0, stream>>>(feat, featbf, out, cnt);
    hist_kernel<<<2048, 256, 0, stream>>>(ei, cnt);
    partial_kernel<<<NPB, 256, 0, stream>>>(cnt, part);
    scanpart_kernel<<<1, 256, 0, stream>>>(part, partx);
    cursor_kernel<<<NPB, 256, 0, stream>>>(cnt, partx, cursor);
    scatter_kernel<<<2048, 256, 0, stream>>>(ei, ea, cursor, rec);
    edge_mfma_kernel<<<GRID, 256, 0, stream>>>(featbf, pos, W, b, rec, out);
    finalize_kernel<<<2048, 256, 0, stream>>>((float*)out, NNODES * COUT);
}

// Round 8
// 176.379 us; speedup vs baseline: 1.5605x; 1.3668x over previous
//
#include <hip/hip_runtime.h>
#include <math.h>

#define NNODES 50000
#define NEDGES 800000
#define COUT 64
#define TILE_E 64
#define NTILES (NEDGES / TILE_E)   // 12500, exact
#define GRID 1024                  // 256 CU x 4 blocks
#define KEY_NEG_INF 0x007FFFFFu    // fkey(-inf)
#define NB1 391                    // coarse buckets (dst>>7) and P1 chunks
#define NB1P 392                   // padded stride
#define CHUNK 2048                 // edges per P1 block
#define P2CAP 2816                 // LDS rec capacity per bucket (mean 2048 + 17 sigma)

typedef short bf16x8 __attribute__((ext_vector_type(8)));
typedef float f32x4 __attribute__((ext_vector_type(4)));
#define MFMA16 __builtin_amdgcn_mfma_f32_16x16x32_bf16

// fp32 -> bf16 RTNE
__device__ __forceinline__ unsigned short f2bf(float x) {
    union { float f; unsigned u; } v; v.f = x;
    unsigned r = v.u + 0x7fffu + ((v.u >> 16) & 1u);
    return (unsigned short)(r >> 16);
}

// order-preserving float -> uint key
__device__ __forceinline__ unsigned fkey(float v) {
    unsigned u = __float_as_uint(v);
    return u ^ ((unsigned)((int)u >> 31) | 0x80000000u);
}

// ---------------------------------------------------------------------------
// prep: feat f32 -> bf16 table; out <- key(-inf)
// ---------------------------------------------------------------------------
__global__ void prep_kernel(const float* __restrict__ feat, unsigned short* __restrict__ featbf,
                            unsigned* __restrict__ out) {
    int i = blockIdx.x * blockDim.x + threadIdx.x;
    int st = gridDim.x * blockDim.x;
    for (int j = i; j < (NNODES * COUT) / 8; j += st) {
        const float4* pp = (const float4*)(feat + (size_t)j * 8);
        float4 x = pp[0], y = pp[1];
        union { unsigned short u[8]; uint4 v; } r;
        r.u[0] = f2bf(x.x); r.u[1] = f2bf(x.y); r.u[2] = f2bf(x.z); r.u[3] = f2bf(x.w);
        r.u[4] = f2bf(y.x); r.u[5] = f2bf(y.y); r.u[6] = f2bf(y.z); r.u[7] = f2bf(y.w);
        ((uint4*)featbf)[j] = r.v;
    }
    for (int j = i; j < NNODES * COUT; j += st) out[j] = KEY_NEG_INF;
}

// ---------------------------------------------------------------------------
// P1a: per-chunk LDS histogram of coarse bucket (dst>>7), coalesced store
// ---------------------------------------------------------------------------
__global__ __launch_bounds__(256) void p1a_kernel(const int* __restrict__ ei,
                                                  unsigned* __restrict__ cnt1) {
    __shared__ unsigned h[NB1];
    const int t = threadIdx.x, blk = blockIdx.x;
    for (int i = t; i < NB1; i += 256) h[i] = 0u;
    __syncthreads();
    const int e0 = blk * CHUNK;
    for (int i = t; i < CHUNK; i += 256) {
        int e = e0 + i;
        if (e < NEDGES) atomicAdd(&h[(unsigned)ei[NEDGES + e] >> 7], 1u);
    }
    __syncthreads();
    for (int i = t; i < NB1; i += 256) cnt1[blk * NB1P + i] = h[i];
}

// ---------------------------------------------------------------------------
// P1b: per bucket b, exclusive scan over blocks of cnt1[blk][b]; totals[b]
// ---------------------------------------------------------------------------
__global__ __launch_bounds__(512) void p1b_kernel(const unsigned* __restrict__ cnt1,
                                                  unsigned* __restrict__ off0,
                                                  unsigned* __restrict__ totals) {
    __shared__ unsigned sh[512];
    const int t = threadIdx.x, b = blockIdx.x;
    unsigned v = (t < NB1) ? cnt1[t * NB1P + b] : 0u;
    sh[t] = v;
    __syncthreads();
    for (int off = 1; off < 512; off <<= 1) {
        unsigned add = (t >= off) ? sh[t - off] : 0u;
        __syncthreads();
        sh[t] += add;
        __syncthreads();
    }
    if (t < NB1) off0[t * NB1P + b] = sh[t] - v;
    if (t == 511) totals[b] = sh[511];
}

// P1c: exclusive scan of totals[391] -> base[392]
__global__ __launch_bounds__(512) void p1c_kernel(const unsigned* __restrict__ totals,
                                                  unsigned* __restrict__ base) {
    __shared__ unsigned sh[512];
    const int t = threadIdx.x;
    unsigned v = (t < NB1) ? totals[t] : 0u;
    sh[t] = v;
    __syncthreads();
    for (int off = 1; off < 512; off <<= 1) {
        unsigned add = (t >= off) ? sh[t - off] : 0u;
        __syncthreads();
        sh[t] += add;
        __syncthreads();
    }
    if (t <= NB1) base[t] = sh[t] - v;   // t==391: v=0 -> total sum
}

// ---------------------------------------------------------------------------
// P1d: scatter edges into coarse-bucket-grouped rec (LDS ranks, no global atomics)
// ---------------------------------------------------------------------------
__global__ __launch_bounds__(256) void p1d_kernel(const int* __restrict__ ei,
                                                  const int* __restrict__ ea,
                                                  const unsigned* __restrict__ off0,
                                                  const unsigned* __restrict__ base,
                                                  int2* __restrict__ rec) {
    __shared__ unsigned h[NB1];
    const int t = threadIdx.x, blk = blockIdx.x;
    for (int i = t; i < NB1; i += 256) h[i] = 0u;
    __syncthreads();
    const int e0 = blk * CHUNK;
    for (int i = t; i < CHUNK; i += 256) {
        int e = e0 + i;
        if (e < NEDGES) {
            int d = ei[NEDGES + e];
            unsigned b = (unsigned)d >> 7;
            unsigned rk = atomicAdd(&h[b], 1u);
            unsigned pos = base[b] + off0[blk * NB1P + b] + rk;
            rec[pos] = make_int2(ei[e] | (ea[e] << 20), d);
        }
    }
}

// ---------------------------------------------------------------------------
// P2: per-bucket full sort by dst (128 bins), in place via LDS buffer
// ---------------------------------------------------------------------------
__global__ __launch_bounds__(512) void p2_kernel(const unsigned* __restrict__ base,
                                                 int2* __restrict__ rec) {
    __shared__ int2 buf[P2CAP];
    __shared__ unsigned hist[128], dbase[128];
    const int t = threadIdx.x, b = blockIdx.x;
    const unsigned lo = base[b];
    int n = (int)(base[b + 1] - lo);
    if (n > P2CAP) n = P2CAP;        // statistically unreachable
    for (int i = t; i < 128; i += 512) hist[i] = 0u;
    __syncthreads();
    for (int i = t; i < n; i += 512) {
        int2 r = rec[lo + i];
        buf[i] = r;
        atomicAdd(&hist[r.y & 127], 1u);
    }
    __syncthreads();
    if (t < 64) {                    // wave 0: scan 128 bins, 2 per lane
        unsigned h0 = hist[2 * t], h1 = hist[2 * t + 1];
        unsigned s = h0 + h1;
        unsigned inc = s;
        #pragma unroll
        for (int off = 1; off < 64; off <<= 1) {
            unsigned nb = __shfl_up(inc, off, 64);
            if (t >= off) inc += nb;
        }
        unsigned excl = inc - s;
        dbase[2 * t] = excl;
        dbase[2 * t + 1] = excl + h0;
    }
    __syncthreads();
    for (int i = t; i < 128; i += 512) hist[i] = 0u;   // reuse as rank counters
    __syncthreads();
    for (int i = t; i < n; i += 512) {
        int2 r = buf[i];
        int ld = r.y & 127;
        unsigned rk = atomicAdd(&hist[ld], 1u);
        rec[lo + dbase[ld] + rk] = r;
    }
}

__global__ void finalize_kernel(float* __restrict__ out, int n) {
    int i = blockIdx.x * blockDim.x + threadIdx.x;
    int stride = gridDim.x * blockDim.x;
    for (; i < n; i += stride) {
        unsigned k = ((unsigned*)out)[i];
        unsigned u = (k & 0x80000000u) ? (k ^ 0x80000000u) : ~k;
        out[i] = (u == 0xFF800000u) ? 0.0f : __uint_as_float(u);
    }
}

// ---------------------------------------------------------------------------
// MFMA edge kernel over dst-sorted records — UNCHANGED from round 7.
// ---------------------------------------------------------------------------
__global__ __launch_bounds__(256, 4) void edge_mfma_kernel(
    const unsigned short* __restrict__ featbf, const float* __restrict__ pos,
    const float* __restrict__ W, const float* __restrict__ b,
    const int2* __restrict__ rec, unsigned* __restrict__ out)
{
    __shared__ char SMEM[37376];
    bf16x8*   Amsg = (bf16x8*)SMEM;               // [20][64] 16B units, 20480 B
    unsigned* Kt   = (unsigned*)(SMEM + 20480);   // [4096], 16384 B
    int*      dstv = (int*)(SMEM + 36864);        // [2][64]

    const int tid = threadIdx.x;
    const int lane = tid & 63, w = tid >> 6;
    const int rg = w >> 1, cg = w & 1;
    const int la = lane & 15, lh = lane >> 4;
    const bf16x8 zero8 = {0, 0, 0, 0, 0, 0, 0, 0};

    // ---- stage W_aug [col j][k 0..159] bf16 into SMEM (one-time) ----
    {
        unsigned short* Ws = (unsigned short*)SMEM;   // 64*160*2 = 20480 B
        for (int idx = tid; idx < 160 * 64; idx += 256) {
            int k = idx >> 6, j = idx & 63;           // coalesced over j
            int t = (k >= 80);
            int kk = k - t * 80;
            float v = 0.0f;
            if (kk < 71)       v = W[(t * 71 + kk) * 64 + j];
            else if (kk == 71) v = b[t * 64 + j];
            Ws[j * 160 + k] = f2bf(v);
        }
    }
    __syncthreads();
    bf16x8 wb0[5], wb1[5];
    {
        const bf16x8* Wv = (const bf16x8*)SMEM;       // frag = Wv[col*20 + slot]
        const int c0 = cg * 32 + la, c1 = c0 + 16;
        #pragma unroll
        for (int ks = 0; ks < 5; ++ks) {
            wb0[ks] = Wv[c0 * 20 + ks * 4 + lh];
            wb1[ks] = Wv[c1 * 20 + ks * 4 + lh];
        }
    }
    __syncthreads();                                  // all frags held
    // one-time zero of slots 9 and 19 (never written in the loop)
    if (tid < 128) {
        Amsg[(9 + (tid >> 6) * 10) * 64 + (tid & 63)] = zero8;
    }
    __syncthreads();

    const int row = tid >> 2, c = tid & 3;

    int it = 0;
    for (int tile = blockIdx.x; tile < NTILES; tile += GRID, ++it) {
        const int p = it & 1;
        // ---------------- stage 64 sorted edges ----------------
        const int2 r2 = rec[tile * TILE_E + row];
        const int src = r2.x & 0xFFFFF;
        const int t = r2.x >> 20;
        const int ot = 1 - t;

        const uint4* g = (const uint4*)(featbf + (size_t)src * 64);   // 8x16B
        uint4 q0 = g[2 * c], q1 = g[2 * c + 1];
        *(uint4*)&Amsg[(t * 10 + 2 * c) * 64 + row]     = q0;
        *(uint4*)&Amsg[(t * 10 + 2 * c + 1) * 64 + row] = q1;
        Amsg[(ot * 10 + 2 * c) * 64 + row]     = zero8;
        Amsg[(ot * 10 + 2 * c + 1) * 64 + row] = zero8;

        if (c == 0) {
            int dst = r2.y;
            float ps0 = pos[src * 3], ps1 = pos[src * 3 + 1], ps2 = pos[src * 3 + 2];
            float d0 = pos[dst * 3] - ps0, d1 = pos[dst * 3 + 1] - ps1, d2 = pos[dst * 3 + 2] - ps2;
            float dist = sqrtf(d0 * d0 + d1 * d1 + d2 * d2);
            union { bf16x8 v; unsigned short u[8]; } pt;
            pt.u[0] = f2bf(ps0); pt.u[1] = f2bf(ps1); pt.u[2] = f2bf(ps2);
            pt.u[3] = f2bf(d0);  pt.u[4] = f2bf(d1);  pt.u[5] = f2bf(d2);
            pt.u[6] = f2bf(dist); pt.u[7] = f2bf(1.0f);
            Amsg[(t * 10 + 8) * 64 + row] = pt.v;
        } else if (c == 1) {
            Amsg[(ot * 10 + 8) * 64 + row] = zero8;
        } else if (c == 3) {
            dstv[p * 64 + row] = r2.y;
        }
        __syncthreads();                                   // B1: tile staged

        // ---------------- mfma: 32x32 tile per wave, W from regs ----------------
        f32x4 acc00 = {0,0,0,0}, acc01 = {0,0,0,0}, acc10 = {0,0,0,0}, acc11 = {0,0,0,0};
        const int r0 = rg * 32 + la, r1 = r0 + 16;
        #pragma unroll
        for (int ks = 0; ks < 5; ++ks) {
            bf16x8 a0 = Amsg[(ks * 4 + lh) * 64 + r0];
            bf16x8 a1 = Amsg[(ks * 4 + lh) * 64 + r1];
            acc00 = MFMA16(a0, wb0[ks], acc00, 0, 0, 0);
            acc01 = MFMA16(a0, wb1[ks], acc01, 0, 0, 0);
            acc10 = MFMA16(a1, wb0[ks], acc10, 0, 0, 0);
            acc11 = MFMA16(a1, wb1[ks], acc11, 0, 0, 0);
        }

        // ---------------- keys -> Kt (swizzled, 2-way free) ----------------
        const int col0 = cg * 32 + la, col1 = col0 + 16;
        #pragma unroll
        for (int i = 0; i < 4; ++i) {
            int e0 = rg * 32 + lh * 4 + i, e1 = e0 + 16;
            Kt[e0 * 64 + (col0 ^ ((e0 << 2) & 31))] = fkey(acc00[i]);
            Kt[e0 * 64 + (col1 ^ ((e0 << 2) & 31))] = fkey(acc01[i]);
            Kt[e1 * 64 + (col0 ^ ((e1 << 2) & 31))] = fkey(acc10[i]);
            Kt[e1 * 64 + (col1 ^ ((e1 << 2) & 31))] = fkey(acc11[i]);
        }
        __syncthreads();                                   // B2: keys visible

        // ---- segmented max: thread (col, 16-row quarter), sorted dsts ----
        {
            const int colr = tid & 63;
            const int rbeg = (tid >> 6) * 16;
            unsigned cur = Kt[rbeg * 64 + (colr ^ ((rbeg << 2) & 31))];
            int curd = dstv[p * 64 + rbeg];
            #pragma unroll
            for (int r = rbeg + 1; r < rbeg + 16; ++r) {
                unsigned k = Kt[r * 64 + (colr ^ ((r << 2) & 31))];
                int d = dstv[p * 64 + r];
                if (d != curd) {
                    atomicMax(out + (size_t)curd * COUT + colr, cur);
                    curd = d; cur = k;
                } else {
                    cur = (k > cur) ? k : cur;
                }
            }
            atomicMax(out + (size_t)curd * COUT + colr, cur);
        }
        // next staging: Amsg writes land in slots read before B2; dstv is
        // double-buffered; Kt(n+1) writes are gated by B1(n+1).
    }
}

extern "C" void kernel_launch(void* const* d_in, const int* in_sizes, int n_in,
                              void* d_out, int out_size, void* d_ws, size_t ws_size,
                              hipStream_t stream) {
    const float* feat = (const float*)d_in[0];
    const float* pos  = (const float*)d_in[1];
    const float* W    = (const float*)d_in[2];
    const float* b    = (const float*)d_in[3];
    const int*   ei   = (const int*)d_in[4];
    const int*   ea   = (const int*)d_in[5];
    unsigned* out = (unsigned*)d_out;

    // ws: featbf 6.4MB | rec 6.4MB | cnt1 612KB | off0 612KB | totals | base
    unsigned short* featbf = (unsigned short*)d_ws;
    int2*     rec    = (int2*)((char*)d_ws + (size_t)NNODES * COUT * 2);
    unsigned* cnt1   = (unsigned*)(rec + NEDGES);
    unsigned* off0   = cnt1 + NB1 * NB1P;
    unsigned* totals = off0 + NB1 * NB1P;
    unsigned* base   = totals + NB1P;

    prep_kernel<<<2048, 256, 0, stream>>>(feat, featbf, out);
    p1a_kernel<<<NB1, 256, 0, stream>>>(ei, cnt1);
    p1b_kernel<<<NB1, 512, 0, stream>>>(cnt1, off0, totals);
    p1c_kernel<<<1, 512, 0, stream>>>(totals, base);
    p1d_kernel<<<NB1, 256, 0, stream>>>(ei, ea, off0, base, rec);
    p2_kernel<<<NB1, 512, 0, stream>>>(base, rec);
    edge_mfma_kernel<<<GRID, 256, 0, stream>>>(featbf, pos, W, b, rec, out);
    finalize_kernel<<<2048, 256, 0, stream>>>((float*)out, NNODES * COUT);
}